// Round 2
// baseline (3113.392 us; speedup 1.0000x reference)
//
#include <hip/hip_runtime.h>

#define N_NODES 100000
#define DIM     128
#define HID     256
#define BN_EPS  1e-5f

// h[i] = (1+eps) * x[i]   (h lives in d_out, fully overwritten later by gemm2)
__global__ void init_h_kernel(const float* __restrict__ x, const float* __restrict__ eps,
                              float* __restrict__ h) {
    long long i = (long long)blockIdx.x * blockDim.x + threadIdx.x;  // float4 index
    float s = 1.0f + eps[0];
    float4 v = ((const float4*)x)[i];
    v.x *= s; v.y *= s; v.z *= s; v.w *= s;
    ((float4*)h)[i] = v;
}

// 32 threads per edge, 4 floats per thread -> 128 dims
__global__ void scatter_edges_kernel(const float* __restrict__ x, const int* __restrict__ src,
                                     const int* __restrict__ dst, float* __restrict__ h, int nE) {
    long long tid = (long long)blockIdx.x * blockDim.x + threadIdx.x;
    int part = (int)(tid & 31);
    long long e = tid >> 5;
    if (e >= nE) return;
    int s = src[e];
    int d = dst[e];
    float4 v = ((const float4*)(x + (long long)s * DIM))[part];
    float* hd = h + (long long)d * DIM + part * 4;
    atomicAdd(hd + 0, v.x);
    atomicAdd(hd + 1, v.y);
    atomicAdd(hd + 2, v.z);
    atomicAdd(hd + 3, v.w);
}

// GEMM1: h[N,128] @ W1[128,256] + BN1 + ReLU -> h1[N,256]
// block: 256 threads, 32 rows; thread t owns column t for all 32 rows.
#define ROWS1 32
__global__ __launch_bounds__(256) void gemm1_kernel(
    const float* __restrict__ h, const float* __restrict__ W1,
    const float* __restrict__ b1, const float* __restrict__ g1,
    const float* __restrict__ be1, const float* __restrict__ m1,
    const float* __restrict__ v1, float* __restrict__ h1) {
    __shared__ float sh[ROWS1][DIM];
    int row0 = blockIdx.x * ROWS1;
    int t = threadIdx.x;
    // stage 32x128 tile: 1024 float4s / 256 threads = 4 each
    for (int i = t; i < ROWS1 * (DIM / 4); i += 256) {
        int r = i >> 5, c4 = i & 31;
        ((float4*)sh[r])[c4] = ((const float4*)(h + (long long)(row0 + r) * DIM))[c4];
    }
    __syncthreads();
    int col = t;
    float acc[ROWS1];
#pragma unroll
    for (int r = 0; r < ROWS1; ++r) acc[r] = 0.f;
    for (int k = 0; k < DIM; k += 4) {
        float w0 = W1[(k + 0) * HID + col];
        float w1 = W1[(k + 1) * HID + col];
        float w2 = W1[(k + 2) * HID + col];
        float w3 = W1[(k + 3) * HID + col];
#pragma unroll
        for (int r = 0; r < ROWS1; ++r) {
            float4 hv = *((const float4*)&sh[r][k]);
            acc[r] = fmaf(hv.x, w0, acc[r]);
            acc[r] = fmaf(hv.y, w1, acc[r]);
            acc[r] = fmaf(hv.z, w2, acc[r]);
            acc[r] = fmaf(hv.w, w3, acc[r]);
        }
    }
    float scale = g1[col] * rsqrtf(v1[col] + BN_EPS);
    float shift = (b1[col] - m1[col]) * scale + be1[col];
#pragma unroll
    for (int r = 0; r < ROWS1; ++r) {
        h1[(long long)(row0 + r) * HID + col] = fmaxf(0.f, fmaf(acc[r], scale, shift));
    }
}

// GEMM2: h1[N,256] @ W2[256,128] + BN2 + ReLU -> out[N,128]
// block: 128 threads, 32 rows; thread t owns column t for all 32 rows.
#define ROWS2 32
__global__ __launch_bounds__(128) void gemm2_kernel(
    const float* __restrict__ h1, const float* __restrict__ W2,
    const float* __restrict__ b2, const float* __restrict__ g2,
    const float* __restrict__ be2, const float* __restrict__ m2,
    const float* __restrict__ v2, float* __restrict__ out) {
    __shared__ float sh[ROWS2][HID];
    int row0 = blockIdx.x * ROWS2;
    int t = threadIdx.x;
    // stage 32x256 tile: 2048 float4s / 128 threads = 16 each
    for (int i = t; i < ROWS2 * (HID / 4); i += 128) {
        int r = i >> 6, c4 = i & 63;
        ((float4*)sh[r])[c4] = ((const float4*)(h1 + (long long)(row0 + r) * HID))[c4];
    }
    __syncthreads();
    int col = t;
    float acc[ROWS2];
#pragma unroll
    for (int r = 0; r < ROWS2; ++r) acc[r] = 0.f;
    for (int k = 0; k < HID; k += 4) {
        float w0 = W2[(k + 0) * DIM + col];
        float w1 = W2[(k + 1) * DIM + col];
        float w2 = W2[(k + 2) * DIM + col];
        float w3 = W2[(k + 3) * DIM + col];
#pragma unroll
        for (int r = 0; r < ROWS2; ++r) {
            float4 hv = *((const float4*)&sh[r][k]);
            acc[r] = fmaf(hv.x, w0, acc[r]);
            acc[r] = fmaf(hv.y, w1, acc[r]);
            acc[r] = fmaf(hv.z, w2, acc[r]);
            acc[r] = fmaf(hv.w, w3, acc[r]);
        }
    }
    float scale = g2[col] * rsqrtf(v2[col] + BN_EPS);
    float shift = (b2[col] - m2[col]) * scale + be2[col];
#pragma unroll
    for (int r = 0; r < ROWS2; ++r) {
        out[(long long)(row0 + r) * DIM + col] = fmaxf(0.f, fmaf(acc[r], scale, shift));
    }
}

extern "C" void kernel_launch(void* const* d_in, const int* in_sizes, int n_in,
                              void* d_out, int out_size, void* d_ws, size_t ws_size,
                              hipStream_t stream) {
    const float* x   = (const float*)d_in[0];
    const float* eps = (const float*)d_in[1];
    const float* W1  = (const float*)d_in[2];
    const float* b1  = (const float*)d_in[3];
    const float* g1  = (const float*)d_in[4];
    const float* be1 = (const float*)d_in[5];
    const float* m1  = (const float*)d_in[6];
    const float* v1  = (const float*)d_in[7];
    const float* W2  = (const float*)d_in[8];
    const float* b2  = (const float*)d_in[9];
    const float* g2  = (const float*)d_in[10];
    const float* be2 = (const float*)d_in[11];
    const float* m2  = (const float*)d_in[12];
    const float* v2  = (const float*)d_in[13];
    const int*   ei  = (const int*)d_in[14];
    int nE = in_sizes[14] / 2;
    const int* src = ei;
    const int* dst = ei + nE;

    float* h  = (float*)d_out;           // N x 128 temp (overwritten by gemm2 at the end)
    float* h1 = (float*)d_ws;            // N x 256 fp32 = 102.4 MB

    // 1) h = (1+eps)*x
    {
        long long n4 = (long long)N_NODES * DIM / 4;   // 3.2M
        int blocks = (int)(n4 / 256);                  // exact
        init_h_kernel<<<blocks, 256, 0, stream>>>(x, eps, h);
    }
    // 2) scatter-add edges
    {
        long long threads = (long long)nE * 32;
        int blocks = (int)((threads + 255) / 256);
        scatter_edges_kernel<<<blocks, 256, 0, stream>>>(x, src, dst, h, nE);
    }
    // 3) GEMM1 + BN + ReLU
    gemm1_kernel<<<N_NODES / ROWS1, 256, 0, stream>>>(h, W1, b1, g1, be1, m1, v1, h1);
    // 4) GEMM2 + BN + ReLU
    gemm2_kernel<<<N_NODES / ROWS2, 128, 0, stream>>>(h1, W2, b2, g2, be2, m2, v2,
                                                      (float*)d_out);
}

// Round 3
// 667.386 us; speedup vs baseline: 4.6651x; 4.6651x over previous
//
#include <hip/hip_runtime.h>

#define N_NODES 100000
#define DIM     128
#define HID     256
#define BN_EPS  1e-5f
#define SCAN_B  1024

// ---------------- CSR build ----------------
__global__ void hist_kernel(const int* __restrict__ dst, int* __restrict__ deg, int nE) {
    int e = blockIdx.x * blockDim.x + threadIdx.x;
    if (e < nE) atomicAdd(&deg[dst[e]], 1);
}

__global__ __launch_bounds__(SCAN_B) void scan1_kernel(const int* __restrict__ deg,
                                                       int* __restrict__ excl,
                                                       int* __restrict__ bsum, int n) {
    __shared__ int tmp[SCAN_B];
    int tid = threadIdx.x;
    int i = blockIdx.x * SCAN_B + tid;
    int v = (i < n) ? deg[i] : 0;
    tmp[tid] = v;
    __syncthreads();
    for (int off = 1; off < SCAN_B; off <<= 1) {
        int t = (tid >= off) ? tmp[tid - off] : 0;
        __syncthreads();
        tmp[tid] += t;
        __syncthreads();
    }
    if (i < n) excl[i] = tmp[tid] - v;          // exclusive within block
    if (tid == SCAN_B - 1) bsum[blockIdx.x] = tmp[tid];
}

__global__ void scan2_kernel(int* bsum, int nb) {
    if (threadIdx.x == 0 && blockIdx.x == 0) {
        int acc = 0;
        for (int b = 0; b < nb; ++b) { int t = bsum[b]; bsum[b] = acc; acc += t; }
    }
}

__global__ __launch_bounds__(SCAN_B) void scan3_kernel(const int* __restrict__ excl,
                                                       const int* __restrict__ bsum,
                                                       int* __restrict__ rowptr, int n, int nE) {
    int i = blockIdx.x * SCAN_B + threadIdx.x;
    if (i < n) rowptr[i] = excl[i] + bsum[blockIdx.x];
    if (i == 0) rowptr[n] = nE;
}

__global__ void fill_kernel(const int* __restrict__ src, const int* __restrict__ dst,
                            int* __restrict__ cursor, int* __restrict__ csr_src, int nE) {
    int e = blockIdx.x * blockDim.x + threadIdx.x;
    if (e < nE) {
        int d = dst[e];
        int pos = atomicAdd(&cursor[d], 1);
        csr_src[pos] = src[e];
    }
}

// ---------------- Gather-sum: one wave per node ----------------
// h[node] = (1+eps)*x[node] + sum_{s in neigh(node)} x[s]
__global__ __launch_bounds__(256) void gather_kernel(const float* __restrict__ x,
                                                     const float* __restrict__ epsp,
                                                     const int* __restrict__ rowptr,
                                                     const int* __restrict__ csr_src,
                                                     float* __restrict__ h) {
    int wv = blockIdx.x * 4 + (threadIdx.x >> 6);   // node id
    int lane = threadIdx.x & 63;
    if (wv >= N_NODES) return;
    int beg = rowptr[wv], end = rowptr[wv + 1];
    const float2* xp = (const float2*)x;
    float ax = 0.f, ay = 0.f;
    for (int j = beg; j < end; ++j) {
        int s = csr_src[j];                         // wave-uniform
        float2 v = xp[(long long)s * 64 + lane];    // 512B coalesced row read
        ax += v.x; ay += v.y;
    }
    float sc = 1.f + epsp[0];
    float2 xv = xp[(long long)wv * 64 + lane];
    float2 o;
    o.x = fmaf(sc, xv.x, ax);
    o.y = fmaf(sc, xv.y, ay);
    ((float2*)h)[(long long)wv * 64 + lane] = o;
}

// ---------------- Fused MLP: GEMM1+BN+ReLU -> LDS -> GEMM2+BN+ReLU ----------------
// 256 threads, 32 rows per block. In-place safe on h==out (block reads its rows
// fully into LDS before writing them).
__global__ __launch_bounds__(256) void mlp_kernel(
    const float* __restrict__ h,
    const float* __restrict__ W1, const float* __restrict__ b1,
    const float* __restrict__ g1, const float* __restrict__ be1,
    const float* __restrict__ m1, const float* __restrict__ v1,
    const float* __restrict__ W2, const float* __restrict__ b2,
    const float* __restrict__ g2, const float* __restrict__ be2,
    const float* __restrict__ m2, const float* __restrict__ v2,
    float* __restrict__ out) {
    __shared__ float sh[32][DIM];    // 16 KB
    __shared__ float sh1[32][HID];   // 32 KB
    int row0 = blockIdx.x * 32;
    int t = threadIdx.x;
    for (int i = t; i < 32 * (DIM / 4); i += 256) {
        int r = i >> 5, c4 = i & 31;
        ((float4*)sh[r])[c4] = ((const float4*)(h + (long long)(row0 + r) * DIM))[c4];
    }
    __syncthreads();
    // ---- GEMM1: col = t (0..255), 32 rows ----
    {
        int col = t;
        float acc[32];
#pragma unroll
        for (int r = 0; r < 32; ++r) acc[r] = 0.f;
        for (int k = 0; k < DIM; k += 4) {
            float w0 = W1[(k + 0) * HID + col];
            float w1 = W1[(k + 1) * HID + col];
            float w2 = W1[(k + 2) * HID + col];
            float w3 = W1[(k + 3) * HID + col];
#pragma unroll
            for (int r = 0; r < 32; ++r) {
                float4 hv = *((const float4*)&sh[r][k]);
                acc[r] = fmaf(hv.x, w0, acc[r]);
                acc[r] = fmaf(hv.y, w1, acc[r]);
                acc[r] = fmaf(hv.z, w2, acc[r]);
                acc[r] = fmaf(hv.w, w3, acc[r]);
            }
        }
        float scale = g1[col] * rsqrtf(v1[col] + BN_EPS);
        float shift = (b1[col] - m1[col]) * scale + be1[col];
#pragma unroll
        for (int r = 0; r < 32; ++r)
            sh1[r][col] = fmaxf(0.f, fmaf(acc[r], scale, shift));
    }
    __syncthreads();
    // ---- GEMM2: col = t&127, rows split in halves of 16 ----
    {
        int col = t & 127;
        int rbase = (t >> 7) * 16;
        float acc2[16];
#pragma unroll
        for (int r = 0; r < 16; ++r) acc2[r] = 0.f;
        for (int k = 0; k < HID; k += 4) {
            float w0 = W2[(k + 0) * DIM + col];
            float w1 = W2[(k + 1) * DIM + col];
            float w2 = W2[(k + 2) * DIM + col];
            float w3 = W2[(k + 3) * DIM + col];
#pragma unroll
            for (int r = 0; r < 16; ++r) {
                float4 hv = *((const float4*)&sh1[rbase + r][k]);
                acc2[r] = fmaf(hv.x, w0, acc2[r]);
                acc2[r] = fmaf(hv.y, w1, acc2[r]);
                acc2[r] = fmaf(hv.z, w2, acc2[r]);
                acc2[r] = fmaf(hv.w, w3, acc2[r]);
            }
        }
        float scale = g2[col] * rsqrtf(v2[col] + BN_EPS);
        float shift = (b2[col] - m2[col]) * scale + be2[col];
#pragma unroll
        for (int r = 0; r < 16; ++r)
            out[(long long)(row0 + rbase + r) * DIM + col] =
                fmaxf(0.f, fmaf(acc2[r], scale, shift));
    }
}

extern "C" void kernel_launch(void* const* d_in, const int* in_sizes, int n_in,
                              void* d_out, int out_size, void* d_ws, size_t ws_size,
                              hipStream_t stream) {
    const float* x   = (const float*)d_in[0];
    const float* eps = (const float*)d_in[1];
    const float* W1  = (const float*)d_in[2];
    const float* b1  = (const float*)d_in[3];
    const float* g1  = (const float*)d_in[4];
    const float* be1 = (const float*)d_in[5];
    const float* m1  = (const float*)d_in[6];
    const float* v1  = (const float*)d_in[7];
    const float* W2  = (const float*)d_in[8];
    const float* b2  = (const float*)d_in[9];
    const float* g2  = (const float*)d_in[10];
    const float* be2 = (const float*)d_in[11];
    const float* m2  = (const float*)d_in[12];
    const float* v2  = (const float*)d_in[13];
    const int*   ei  = (const int*)d_in[14];
    int nE = in_sizes[14] / 2;
    const int* src = ei;
    const int* dst = ei + nE;

    // workspace layout (512B-aligned offsets)
    char* ws = (char*)d_ws;
    int* rowptr  = (int*)(ws + 0);         // (N+1) ints
    int* deg     = (int*)(ws + 400896);    // N ints
    int* excl    = (int*)(ws + 801792);    // N ints
    int* bsum    = (int*)(ws + 1202688);   // 98 ints
    int* cursor  = (int*)(ws + 1203200);   // N ints
    int* csr_src = (int*)(ws + 1604096);   // nE ints (6.4 MB)

    float* h = (float*)d_out;  // aggregated features, overwritten in-place by mlp

    int nb_scan = (N_NODES + SCAN_B - 1) / SCAN_B;  // 98

    // 1) CSR build
    hipMemsetAsync(deg, 0, N_NODES * sizeof(int), stream);
    hist_kernel<<<(nE + 255) / 256, 256, 0, stream>>>(dst, deg, nE);
    scan1_kernel<<<nb_scan, SCAN_B, 0, stream>>>(deg, excl, bsum, N_NODES);
    scan2_kernel<<<1, 64, 0, stream>>>(bsum, nb_scan);
    scan3_kernel<<<nb_scan, SCAN_B, 0, stream>>>(excl, bsum, rowptr, N_NODES, nE);
    hipMemcpyAsync(cursor, rowptr, N_NODES * sizeof(int), hipMemcpyDeviceToDevice, stream);
    fill_kernel<<<(nE + 255) / 256, 256, 0, stream>>>(src, dst, cursor, csr_src, nE);

    // 2) gather-sum + (1+eps)*x
    gather_kernel<<<(N_NODES + 3) / 4, 256, 0, stream>>>(x, eps, rowptr, csr_src, h);

    // 3) fused MLP
    mlp_kernel<<<N_NODES / 32, 256, 0, stream>>>(h, W1, b1, g1, be1, m1, v1,
                                                 W2, b2, g2, be2, m2, v2, (float*)d_out);
}

// Round 5
// 587.838 us; speedup vs baseline: 5.2963x; 1.1353x over previous
//
#include <hip/hip_runtime.h>

#define N_NODES 100000
#define DIM     128
#define HID     256
#define BN_EPS  1e-5f
#define SCAN_B  1024

typedef short  short8 __attribute__((ext_vector_type(8)));
typedef float  f32x4  __attribute__((ext_vector_type(4)));

static __device__ __forceinline__ unsigned short f2bf(float f) {
    unsigned int u = __builtin_bit_cast(unsigned int, f);
    unsigned int r = (u + 0x7fffu + ((u >> 16) & 1u)) >> 16;   // RNE
    return (unsigned short)r;
}
static __device__ __forceinline__ float bf2f(unsigned short h) {
    unsigned int u = ((unsigned int)h) << 16;
    return __builtin_bit_cast(float, u);
}
static __device__ __forceinline__ f32x4 mfma16(short8 a, short8 b, f32x4 c) {
    return __builtin_amdgcn_mfma_f32_16x16x32_bf16(a, b, c, 0, 0, 0);
}

// ---------------- CSR build ----------------
__global__ void hist_kernel(const int* __restrict__ dst, int* __restrict__ deg, int nE) {
    int e = blockIdx.x * blockDim.x + threadIdx.x;
    if (e < nE) atomicAdd(&deg[dst[e]], 1);
}

__global__ __launch_bounds__(SCAN_B) void scan1_kernel(const int* __restrict__ deg,
                                                       int* __restrict__ excl,
                                                       int* __restrict__ bsum, int n) {
    __shared__ int tmp[SCAN_B];
    int tid = threadIdx.x;
    int i = blockIdx.x * SCAN_B + tid;
    int v = (i < n) ? deg[i] : 0;
    tmp[tid] = v;
    __syncthreads();
    for (int off = 1; off < SCAN_B; off <<= 1) {
        int t = (tid >= off) ? tmp[tid - off] : 0;
        __syncthreads();
        tmp[tid] += t;
        __syncthreads();
    }
    if (i < n) excl[i] = tmp[tid] - v;
    if (tid == SCAN_B - 1) bsum[blockIdx.x] = tmp[tid];
}

__global__ void scan2_kernel(int* bsum, int nb) {
    if (threadIdx.x == 0 && blockIdx.x == 0) {
        int acc = 0;
        for (int b = 0; b < nb; ++b) { int t = bsum[b]; bsum[b] = acc; acc += t; }
    }
}

__global__ __launch_bounds__(SCAN_B) void scan3_kernel(const int* __restrict__ excl,
                                                       const int* __restrict__ bsum,
                                                       int* __restrict__ rowptr, int n, int nE) {
    int i = blockIdx.x * SCAN_B + threadIdx.x;
    if (i < n) rowptr[i] = excl[i] + bsum[blockIdx.x];
    if (i == 0) rowptr[n] = nE;
}

__global__ void fill_kernel(const int* __restrict__ src, const int* __restrict__ dst,
                            int* __restrict__ cursor, int* __restrict__ csr_src, int nE) {
    int e = blockIdx.x * blockDim.x + threadIdx.x;
    if (e < nE) {
        int d = dst[e];
        int pos = atomicAdd(&cursor[d], 1);
        csr_src[pos] = src[e];
    }
}

// ---------------- Weight prep: transpose + bf16 hi/lo split + BN fold ----------------
__global__ __launch_bounds__(256) void prep_kernel(
    const float* __restrict__ W1, const float* __restrict__ W2,
    const float* __restrict__ b1, const float* __restrict__ g1,
    const float* __restrict__ be1, const float* __restrict__ m1, const float* __restrict__ v1,
    const float* __restrict__ b2, const float* __restrict__ g2,
    const float* __restrict__ be2, const float* __restrict__ m2, const float* __restrict__ v2,
    unsigned short* __restrict__ W1T_hi, unsigned short* __restrict__ W1T_lo,
    unsigned short* __restrict__ W2T_hi, unsigned short* __restrict__ W2T_lo,
    float* __restrict__ scale1, float* __restrict__ shift1,
    float* __restrict__ scale2, float* __restrict__ shift2) {
    int i = blockIdx.x * 256 + threadIdx.x;   // 0..32767
    {
        int col = i >> 7, k = i & 127;        // W1T[col][k] = W1[k][col]
        float x = W1[k * HID + col];
        unsigned short hi = f2bf(x);
        unsigned short lo = f2bf(x - bf2f(hi));
        W1T_hi[i] = hi; W1T_lo[i] = lo;
    }
    {
        int col = i >> 8, k = i & 255;        // W2T[col][k] = W2[k][col]
        float x = W2[k * DIM + col];
        unsigned short hi = f2bf(x);
        unsigned short lo = f2bf(x - bf2f(hi));
        W2T_hi[i] = hi; W2T_lo[i] = lo;
    }
    if (i < HID) {
        float sc = g1[i] * rsqrtf(v1[i] + BN_EPS);
        scale1[i] = sc;
        shift1[i] = (b1[i] - m1[i]) * sc + be1[i];
    }
    if (i < DIM) {
        float sc = g2[i] * rsqrtf(v2[i] + BN_EPS);
        scale2[i] = sc;
        shift2[i] = (b2[i] - m2[i]) * sc + be2[i];
    }
}

// ---------------- Gather-sum: one wave per node ----------------
__global__ __launch_bounds__(256) void gather_kernel(const float* __restrict__ x,
                                                     const float* __restrict__ epsp,
                                                     const int* __restrict__ rowptr,
                                                     const int* __restrict__ csr_src,
                                                     float* __restrict__ h) {
    int wv = blockIdx.x * 4 + (threadIdx.x >> 6);
    int lane = threadIdx.x & 63;
    if (wv >= N_NODES) return;
    int beg = rowptr[wv], end = rowptr[wv + 1];
    const float2* xp = (const float2*)x;
    float ax = 0.f, ay = 0.f;
    for (int j = beg; j < end; ++j) {
        int s = csr_src[j];
        float2 v = xp[(long long)s * 64 + lane];
        ax += v.x; ay += v.y;
    }
    float sc = 1.f + epsp[0];
    float2 xv = xp[(long long)wv * 64 + lane];
    float2 o;
    o.x = fmaf(sc, xv.x, ax);
    o.y = fmaf(sc, xv.y, ay);
    ((float2*)h)[(long long)wv * 64 + lane] = o;
}

// ---------------- Fused MFMA MLP ----------------
// 256 threads = 4 waves, 32 rows/block. Split bf16 (hi/lo) 3-term MFMA.
// wave w: mw=w&1 -> 16-row tile; nh=w>>1 -> GEMM1 128-col half / GEMM2 64-col half.
__global__ __launch_bounds__(256) void mlp_mfma_kernel(
    const float* __restrict__ h,
    const unsigned short* __restrict__ W1T_hi, const unsigned short* __restrict__ W1T_lo,
    const unsigned short* __restrict__ W2T_hi, const unsigned short* __restrict__ W2T_lo,
    const float* __restrict__ scale1, const float* __restrict__ shift1,
    const float* __restrict__ scale2, const float* __restrict__ shift2,
    float* __restrict__ out) {
    __shared__ float sh1[32 * HID];   // 32 KB, XOR-swizzled
    int row0 = blockIdx.x * 32;
    int t = threadIdx.x;
    int w = t >> 6, l = t & 63;
    int l15 = l & 15, q = l >> 4;
    int mw = w & 1;
    int nh = w >> 1;

    // ---- GEMM1: A-frags direct from global (f32 -> bf16 hi/lo in regs) ----
    short8 Ah[4], Al[4];
    {
        const float* arow = h + (long long)(row0 + 16 * mw + l15) * DIM + 8 * q;
#pragma unroll
        for (int ks = 0; ks < 4; ++ks) {
            f32x4 f0 = *(const f32x4*)(arow + 32 * ks);
            f32x4 f1 = *(const f32x4*)(arow + 32 * ks + 4);
            short8 hi, lo;
#pragma unroll
            for (int i = 0; i < 4; ++i) {
                unsigned short h0 = f2bf(f0[i]);
                hi[i] = (short)h0; lo[i] = (short)f2bf(f0[i] - bf2f(h0));
                unsigned short h1v = f2bf(f1[i]);
                hi[i + 4] = (short)h1v; lo[i + 4] = (short)f2bf(f1[i] - bf2f(h1v));
            }
            Ah[ks] = hi; Al[ks] = lo;
        }
    }
    f32x4 C1[8];
#pragma unroll
    for (int nt = 0; nt < 8; ++nt) C1[nt] = (f32x4)(0.f);

#pragma unroll
    for (int nt = 0; nt < 8; ++nt) {
        int col = 128 * nh + 16 * nt + l15;
        const unsigned short* bp = W1T_hi + col * DIM + 8 * q;
        const unsigned short* bq = W1T_lo + col * DIM + 8 * q;
#pragma unroll
        for (int ks = 0; ks < 4; ++ks) {
            short8 bh = *(const short8*)(bp + 32 * ks);
            short8 bl = *(const short8*)(bq + 32 * ks);
            C1[nt] = mfma16(Ah[ks], bh, C1[nt]);
            C1[nt] = mfma16(Ah[ks], bl, C1[nt]);
            C1[nt] = mfma16(Al[ks], bh, C1[nt]);
        }
    }
    // BN1 + ReLU -> swizzled LDS (f32). D layout: col=l15, row=4q+reg.
#pragma unroll
    for (int nt = 0; nt < 8; ++nt) {
        int col = 128 * nh + 16 * nt + l15;
        float sc = scale1[col], sf = shift1[col];
#pragma unroll
        for (int reg = 0; reg < 4; ++reg) {
            int m = 16 * mw + 4 * q + reg;
            int idx = (m * HID + col) ^ ((m & 7) << 2);
            sh1[idx] = fmaxf(0.f, fmaf(C1[nt][reg], sc, sf));
        }
    }
    __syncthreads();

    // ---- GEMM2: A-frags from swizzled LDS ----
    short8 A2h[8], A2l[8];
    {
        int rl = 16 * mw + l15;
        int sw = (rl & 7) << 2;
#pragma unroll
        for (int ks = 0; ks < 8; ++ks) {
            int base = rl * HID + 32 * ks + 8 * q;
            f32x4 f0 = *(const f32x4*)(sh1 + (base ^ sw));
            f32x4 f1 = *(const f32x4*)(sh1 + ((base + 4) ^ sw));
            short8 hi, lo;
#pragma unroll
            for (int i = 0; i < 4; ++i) {
                unsigned short h0 = f2bf(f0[i]);
                hi[i] = (short)h0; lo[i] = (short)f2bf(f0[i] - bf2f(h0));
                unsigned short h1v = f2bf(f1[i]);
                hi[i + 4] = (short)h1v; lo[i + 4] = (short)f2bf(f1[i] - bf2f(h1v));
            }
            A2h[ks] = hi; A2l[ks] = lo;
        }
    }
    // ---- GEMM2: each wave does its 16-row tile x 64-col half (4 n-tiles) ----
    f32x4 C2[4];
#pragma unroll
    for (int nt = 0; nt < 4; ++nt) C2[nt] = (f32x4)(0.f);
#pragma unroll
    for (int nt = 0; nt < 4; ++nt) {
        int col = 64 * nh + 16 * nt + l15;
        const unsigned short* bp = W2T_hi + col * HID + 8 * q;
        const unsigned short* bq = W2T_lo + col * HID + 8 * q;
#pragma unroll
        for (int ks = 0; ks < 8; ++ks) {
            short8 bh = *(const short8*)(bp + 32 * ks);
            short8 bl = *(const short8*)(bq + 32 * ks);
            C2[nt] = mfma16(A2h[ks], bh, C2[nt]);
            C2[nt] = mfma16(A2h[ks], bl, C2[nt]);
            C2[nt] = mfma16(A2l[ks], bh, C2[nt]);
        }
    }
    // BN2 + ReLU -> out
#pragma unroll
    for (int nt = 0; nt < 4; ++nt) {
        int col = 64 * nh + 16 * nt + l15;
        float sc = scale2[col], sf = shift2[col];
#pragma unroll
        for (int reg = 0; reg < 4; ++reg) {
            int row = row0 + 16 * mw + 4 * q + reg;
            out[(long long)row * DIM + col] = fmaxf(0.f, fmaf(C2[nt][reg], sc, sf));
        }
    }
}

extern "C" void kernel_launch(void* const* d_in, const int* in_sizes, int n_in,
                              void* d_out, int out_size, void* d_ws, size_t ws_size,
                              hipStream_t stream) {
    const float* x   = (const float*)d_in[0];
    const float* eps = (const float*)d_in[1];
    const float* W1  = (const float*)d_in[2];
    const float* b1  = (const float*)d_in[3];
    const float* g1  = (const float*)d_in[4];
    const float* be1 = (const float*)d_in[5];
    const float* m1  = (const float*)d_in[6];
    const float* v1  = (const float*)d_in[7];
    const float* W2  = (const float*)d_in[8];
    const float* b2  = (const float*)d_in[9];
    const float* g2  = (const float*)d_in[10];
    const float* be2 = (const float*)d_in[11];
    const float* m2  = (const float*)d_in[12];
    const float* v2  = (const float*)d_in[13];
    const int*   ei  = (const int*)d_in[14];
    int nE = in_sizes[14] / 2;
    const int* src = ei;
    const int* dst = ei + nE;

    // workspace layout (512B-aligned)
    char* ws = (char*)d_ws;
    int* rowptr  = (int*)(ws + 0);          // (N+1) ints
    int* deg     = (int*)(ws + 400896);
    int* excl    = (int*)(ws + 801792);
    int* bsum    = (int*)(ws + 1202688);
    int* cursor  = (int*)(ws + 1203200);
    int* csr_src = (int*)(ws + 1604096);    // nE ints (6.4 MB)
    unsigned short* W1T_hi = (unsigned short*)(ws + 8004608);  // 64 KB
    unsigned short* W1T_lo = (unsigned short*)(ws + 8070144);
    unsigned short* W2T_hi = (unsigned short*)(ws + 8135680);
    unsigned short* W2T_lo = (unsigned short*)(ws + 8201216);
    float* scale1 = (float*)(ws + 8266752);
    float* shift1 = (float*)(ws + 8267776);
    float* scale2 = (float*)(ws + 8268800);
    float* shift2 = (float*)(ws + 8269312);

    float* h = (float*)d_out;   // aggregation result; overwritten in-place by MLP

    int nb_scan = (N_NODES + SCAN_B - 1) / SCAN_B;

    // 0) weight prep (independent)
    prep_kernel<<<128, 256, 0, stream>>>(W1, W2, b1, g1, be1, m1, v1,
                                         b2, g2, be2, m2, v2,
                                         W1T_hi, W1T_lo, W2T_hi, W2T_lo,
                                         scale1, shift1, scale2, shift2);
    // 1) CSR build
    hipMemsetAsync(deg, 0, N_NODES * sizeof(int), stream);
    hist_kernel<<<(nE + 255) / 256, 256, 0, stream>>>(dst, deg, nE);
    scan1_kernel<<<nb_scan, SCAN_B, 0, stream>>>(deg, excl, bsum, N_NODES);
    scan2_kernel<<<1, 64, 0, stream>>>(bsum, nb_scan);
    scan3_kernel<<<nb_scan, SCAN_B, 0, stream>>>(excl, bsum, rowptr, N_NODES, nE);
    hipMemcpyAsync(cursor, rowptr, N_NODES * sizeof(int), hipMemcpyDeviceToDevice, stream);
    fill_kernel<<<(nE + 255) / 256, 256, 0, stream>>>(src, dst, cursor, csr_src, nE);

    // 2) gather-sum + (1+eps)*x
    gather_kernel<<<(N_NODES + 3) / 4, 256, 0, stream>>>(x, eps, rowptr, csr_src, h);

    // 3) fused MFMA MLP (in-place on d_out)
    mlp_mfma_kernel<<<N_NODES / 32, 256, 0, stream>>>(h, W1T_hi, W1T_lo, W2T_hi, W2T_lo,
                                                      scale1, shift1, scale2, shift2,
                                                      (float*)d_out);
}

// Round 7
// 398.121 us; speedup vs baseline: 7.8202x; 1.4765x over previous
//
#include <hip/hip_runtime.h>

#define N_NODES 100000
#define DIM     128
#define HID     256
#define BN_EPS  1e-5f
#define SCAN_B  1024
#define TILES   3125          // N_NODES / 32
#define GEMM_GRID 256

typedef short        short8 __attribute__((ext_vector_type(8)));
typedef float        f32x4  __attribute__((ext_vector_type(4)));
typedef unsigned int u32x4  __attribute__((ext_vector_type(4)));

static __device__ __forceinline__ unsigned int f2bf(float f) {
    unsigned int u = __builtin_bit_cast(unsigned int, f);
    return (u + 0x7fffu + ((u >> 16) & 1u)) >> 16;   // RNE
}
static __device__ __forceinline__ float bf2f(unsigned int h) {
    unsigned int u = h << 16;
    return __builtin_bit_cast(float, u);
}
// pack f32 -> (bf16_hi << 16) | bf16_lo  (split representation, hi+lo ~ exact)
static __device__ __forceinline__ unsigned int packsplit(float f) {
    unsigned int hi = f2bf(f);
    unsigned int lo = f2bf(f - bf2f(hi)) & 0xFFFFu;
    return (hi << 16) | lo;
}
static __device__ __forceinline__ f32x4 mfma16(short8 a, short8 b, f32x4 c) {
    return __builtin_amdgcn_mfma_f32_16x16x32_bf16(a, b, c, 0, 0, 0);
}

// ---------------- CSR build ----------------
__global__ void hist_kernel(const int* __restrict__ dst, int* __restrict__ deg, int nE) {
    int e = blockIdx.x * blockDim.x + threadIdx.x;
    if (e < nE) atomicAdd(&deg[dst[e]], 1);
}

__global__ __launch_bounds__(SCAN_B) void scan1_kernel(const int* __restrict__ deg,
                                                       int* __restrict__ excl,
                                                       int* __restrict__ bsum, int n) {
    __shared__ int tmp[SCAN_B];
    int tid = threadIdx.x;
    int i = blockIdx.x * SCAN_B + tid;
    int v = (i < n) ? deg[i] : 0;
    tmp[tid] = v;
    __syncthreads();
    for (int off = 1; off < SCAN_B; off <<= 1) {
        int t = (tid >= off) ? tmp[tid - off] : 0;
        __syncthreads();
        tmp[tid] += t;
        __syncthreads();
    }
    if (i < n) excl[i] = tmp[tid] - v;
    if (tid == SCAN_B - 1) bsum[blockIdx.x] = tmp[tid];
}

// parallel exclusive scan of block sums (nb <= 128)
__global__ __launch_bounds__(128) void scan2_kernel(int* bsum, int nb) {
    __shared__ int tmp[128];
    int tid = threadIdx.x;
    int v = (tid < nb) ? bsum[tid] : 0;
    tmp[tid] = v;
    __syncthreads();
    for (int off = 1; off < 128; off <<= 1) {
        int t = (tid >= off) ? tmp[tid - off] : 0;
        __syncthreads();
        tmp[tid] += t;
        __syncthreads();
    }
    if (tid < nb) bsum[tid] = tmp[tid] - v;   // exclusive
}

__global__ __launch_bounds__(SCAN_B) void scan3_kernel(const int* __restrict__ excl,
                                                       const int* __restrict__ bsum,
                                                       int* __restrict__ rowptr, int n, int nE) {
    int i = blockIdx.x * SCAN_B + threadIdx.x;
    if (i < n) rowptr[i] = excl[i] + bsum[blockIdx.x];
    if (i == 0) rowptr[n] = nE;
}

__global__ void fill_kernel(const int* __restrict__ src, const int* __restrict__ dst,
                            int* __restrict__ cursor, int* __restrict__ csr_src, int nE) {
    int e = blockIdx.x * blockDim.x + threadIdx.x;
    if (e < nE) {
        int d = dst[e];
        int pos = atomicAdd(&cursor[d], 1);
        csr_src[pos] = src[e];
    }
}

// ---------------- Gather-sum + pack: 32 lanes per node, float4/lane ----------------
// hp[node][d] = packsplit((1+eps)*x[node][d] + sum_neigh x[s][d])
__global__ __launch_bounds__(256) void gather_pack_kernel(
    const float* __restrict__ x, const float* __restrict__ epsp,
    const int* __restrict__ rowptr, const int* __restrict__ csr_src,
    unsigned int* __restrict__ hp) {
    int node = blockIdx.x * 8 + (threadIdx.x >> 5);   // 12500 blocks x 8 nodes, exact
    int lane = threadIdx.x & 31;
    const float4* xp = (const float4*)x;              // row = node*32 + lane
    int beg = rowptr[node], end = rowptr[node + 1];
    float4 a0 = {0.f,0.f,0.f,0.f}, a1 = {0.f,0.f,0.f,0.f};
    float4 a2 = {0.f,0.f,0.f,0.f}, a3 = {0.f,0.f,0.f,0.f};
#define ACC4(A, V) { A.x += V.x; A.y += V.y; A.z += V.z; A.w += V.w; }
    int j = beg;
    for (; j + 4 <= end; j += 4) {                    // 4 independent loads in flight
        int s0 = csr_src[j], s1 = csr_src[j+1], s2 = csr_src[j+2], s3 = csr_src[j+3];
        float4 v0 = xp[s0 * 32 + lane];
        float4 v1 = xp[s1 * 32 + lane];
        float4 v2 = xp[s2 * 32 + lane];
        float4 v3 = xp[s3 * 32 + lane];
        ACC4(a0, v0); ACC4(a1, v1); ACC4(a2, v2); ACC4(a3, v3);
    }
    for (; j < end; ++j) {
        int s = csr_src[j];
        float4 v = xp[s * 32 + lane];
        ACC4(a0, v);
    }
#undef ACC4
    float sc = 1.f + epsp[0];
    float4 xv = xp[node * 32 + lane];
    u32x4 pk;
    pk[0] = packsplit(fmaf(sc, xv.x, a0.x + a1.x + a2.x + a3.x));
    pk[1] = packsplit(fmaf(sc, xv.y, a0.y + a1.y + a2.y + a3.y));
    pk[2] = packsplit(fmaf(sc, xv.z, a0.z + a1.z + a2.z + a3.z));
    pk[3] = packsplit(fmaf(sc, xv.w, a0.w + a1.w + a2.w + a3.w));
    ((u32x4*)hp)[node * 32 + lane] = pk;
}

// ---------------- GEMM1 (persistent, B in regs): h1p = relu(bn1(hp @ W1)) ----------------
// 512 thr = 8 waves: cg=w&3 owns 64 cols, mg=w>>2 owns 16 rows. 2 MFMA/k-step (A split, B bf16).
__global__ __launch_bounds__(512, 2) void gemm1_kernel(
    const unsigned int* __restrict__ hp, const float* __restrict__ W1,
    const float* __restrict__ b1, const float* __restrict__ g1,
    const float* __restrict__ be1, const float* __restrict__ m1,
    const float* __restrict__ v1, unsigned short* __restrict__ h1p) {
    int t = threadIdx.x;
    int w = t >> 6, l = t & 63;
    int l15 = l & 15, q = l >> 4;
    int cg = w & 3, mg = w >> 2;

    // prologue: resident B1 fragments (bf16 of W1), BN fold
    short8 B1[4][4];
    float s1v[4], sh1v[4];
#pragma unroll
    for (int nt = 0; nt < 4; ++nt) {
        int col = 64 * cg + 16 * nt + l15;
#pragma unroll
        for (int ks = 0; ks < 4; ++ks) {
            short8 bh;
#pragma unroll
            for (int i = 0; i < 8; ++i)
                bh[i] = (short)f2bf(W1[(32 * ks + 8 * q + i) * HID + col]);
            B1[nt][ks] = bh;
        }
        float sc = g1[col] * rsqrtf(v1[col] + BN_EPS);
        s1v[nt] = sc;
        sh1v[nt] = (b1[col] - m1[col]) * sc + be1[col];
    }

    for (int tile = blockIdx.x; tile < TILES; tile += GEMM_GRID) {
        int row0 = tile * 32;
        int row = row0 + 16 * mg + l15;
        const u32x4* ap = (const u32x4*)hp + row * 32;
        short8 Ah[4], Al[4];
#pragma unroll
        for (int ks = 0; ks < 4; ++ks) {
            u32x4 p0 = ap[8 * ks + 2 * q];
            u32x4 p1 = ap[8 * ks + 2 * q + 1];
            u32x4 hw, lw;
            hw[0] = (p0[0] >> 16) | (p0[1] & 0xFFFF0000u);
            hw[1] = (p0[2] >> 16) | (p0[3] & 0xFFFF0000u);
            hw[2] = (p1[0] >> 16) | (p1[1] & 0xFFFF0000u);
            hw[3] = (p1[2] >> 16) | (p1[3] & 0xFFFF0000u);
            lw[0] = (p0[0] & 0xFFFFu) | (p0[1] << 16);
            lw[1] = (p0[2] & 0xFFFFu) | (p0[3] << 16);
            lw[2] = (p1[0] & 0xFFFFu) | (p1[1] << 16);
            lw[3] = (p1[2] & 0xFFFFu) | (p1[3] << 16);
            Ah[ks] = __builtin_bit_cast(short8, hw);
            Al[ks] = __builtin_bit_cast(short8, lw);
        }
        f32x4 acc[4];
#pragma unroll
        for (int nt = 0; nt < 4; ++nt) acc[nt] = (f32x4)(0.f);
#pragma unroll
        for (int nt = 0; nt < 4; ++nt)
#pragma unroll
            for (int ks = 0; ks < 4; ++ks) {
                acc[nt] = mfma16(Ah[ks], B1[nt][ks], acc[nt]);
                acc[nt] = mfma16(Al[ks], B1[nt][ks], acc[nt]);
            }
#pragma unroll
        for (int nt = 0; nt < 4; ++nt) {
            int col = 64 * cg + 16 * nt + l15;
#pragma unroll
            for (int reg = 0; reg < 4; ++reg) {
                int orow = row0 + 16 * mg + 4 * q + reg;
                float vv = fmaxf(0.f, fmaf(acc[nt][reg], s1v[nt], sh1v[nt]));
                h1p[orow * HID + col] = (unsigned short)f2bf(vv);
            }
        }
    }
}

// ---------------- GEMM2 (persistent, B split in regs): out = relu(bn2(h1 @ W2)) ----------------
// 512 thr = 8 waves: cg owns 32 cols, mg owns 16 rows. 2 MFMA/k-step (A bf16, B split).
__global__ __launch_bounds__(512, 2) void gemm2_kernel(
    const unsigned short* __restrict__ h1p, const float* __restrict__ W2,
    const float* __restrict__ b2, const float* __restrict__ g2,
    const float* __restrict__ be2, const float* __restrict__ m2,
    const float* __restrict__ v2, float* __restrict__ out) {
    int t = threadIdx.x;
    int w = t >> 6, l = t & 63;
    int l15 = l & 15, q = l >> 4;
    int cg = w & 3, mg = w >> 2;

    short8 B2h[2][8], B2l[2][8];
    float s2v[2], sh2v[2];
#pragma unroll
    for (int nt = 0; nt < 2; ++nt) {
        int col = 32 * cg + 16 * nt + l15;
#pragma unroll
        for (int ks = 0; ks < 8; ++ks) {
            short8 bh, bl;
#pragma unroll
            for (int i = 0; i < 8; ++i) {
                float wv = W2[(32 * ks + 8 * q + i) * DIM + col];
                unsigned int hv = f2bf(wv);
                bh[i] = (short)hv;
                bl[i] = (short)f2bf(wv - bf2f(hv));
            }
            B2h[nt][ks] = bh; B2l[nt][ks] = bl;
        }
        float sc = g2[col] * rsqrtf(v2[col] + BN_EPS);
        s2v[nt] = sc;
        sh2v[nt] = (b2[col] - m2[col]) * sc + be2[col];
    }

    for (int tile = blockIdx.x; tile < TILES; tile += GEMM_GRID) {
        int row0 = tile * 32;
        int row = row0 + 16 * mg + l15;
        const short8* a2p = (const short8*)(h1p + row * HID);
        short8 A2[8];
#pragma unroll
        for (int ks = 0; ks < 8; ++ks) A2[ks] = a2p[4 * ks + q];
        f32x4 acc[2];
        acc[0] = (f32x4)(0.f); acc[1] = (f32x4)(0.f);
#pragma unroll
        for (int nt = 0; nt < 2; ++nt)
#pragma unroll
            for (int ks = 0; ks < 8; ++ks) {
                acc[nt] = mfma16(A2[ks], B2h[nt][ks], acc[nt]);
                acc[nt] = mfma16(A2[ks], B2l[nt][ks], acc[nt]);
            }
#pragma unroll
        for (int nt = 0; nt < 2; ++nt) {
            int col = 32 * cg + 16 * nt + l15;
#pragma unroll
            for (int reg = 0; reg < 4; ++reg) {
                int orow = row0 + 16 * mg + 4 * q + reg;
                out[orow * DIM + col] = fmaxf(0.f, fmaf(acc[nt][reg], s2v[nt], sh2v[nt]));
            }
        }
    }
}

extern "C" void kernel_launch(void* const* d_in, const int* in_sizes, int n_in,
                              void* d_out, int out_size, void* d_ws, size_t ws_size,
                              hipStream_t stream) {
    const float* x   = (const float*)d_in[0];
    const float* eps = (const float*)d_in[1];
    const float* W1  = (const float*)d_in[2];
    const float* b1  = (const float*)d_in[3];
    const float* g1  = (const float*)d_in[4];
    const float* be1 = (const float*)d_in[5];
    const float* m1  = (const float*)d_in[6];
    const float* v1  = (const float*)d_in[7];
    const float* W2  = (const float*)d_in[8];
    const float* b2  = (const float*)d_in[9];
    const float* g2  = (const float*)d_in[10];
    const float* be2 = (const float*)d_in[11];
    const float* m2  = (const float*)d_in[12];
    const float* v2  = (const float*)d_in[13];
    const int*   ei  = (const int*)d_in[14];
    int nE = in_sizes[14] / 2;
    const int* src = ei;
    const int* dst = ei + nE;

    // workspace: CSR arrays + h1p share [0, 51.2MB) — time-disjoint:
    // CSR written/read before gather completes; h1p written by gemm1 afterwards,
    // and every CSR buffer is fully rebuilt at the start of each call.
    char* ws = (char*)d_ws;
    int* rowptr  = (int*)(ws + 0);          // (N+1) ints
    int* deg     = (int*)(ws + 400896);
    int* excl    = (int*)(ws + 801792);
    int* bsum    = (int*)(ws + 1202688);
    int* cursor  = (int*)(ws + 1203200);
    int* csr_src = (int*)(ws + 1604096);    // nE ints (6.4 MB)
    unsigned short* h1p = (unsigned short*)ws;   // [N][256] bf16 = 51.2 MB

    unsigned int* hp = (unsigned int*)d_out;     // packed h, exactly fills d_out

    int nb_scan = (N_NODES + SCAN_B - 1) / SCAN_B;   // 98

    // 1) CSR build
    hipMemsetAsync(deg, 0, N_NODES * sizeof(int), stream);
    hist_kernel<<<(nE + 255) / 256, 256, 0, stream>>>(dst, deg, nE);
    scan1_kernel<<<nb_scan, SCAN_B, 0, stream>>>(deg, excl, bsum, N_NODES);
    scan2_kernel<<<1, 128, 0, stream>>>(bsum, nb_scan);
    scan3_kernel<<<nb_scan, SCAN_B, 0, stream>>>(excl, bsum, rowptr, N_NODES, nE);
    hipMemcpyAsync(cursor, rowptr, N_NODES * sizeof(int), hipMemcpyDeviceToDevice, stream);
    fill_kernel<<<(nE + 255) / 256, 256, 0, stream>>>(src, dst, cursor, csr_src, nE);

    // 2) gather-sum + split-bf16 pack (writes d_out as u32)
    gather_pack_kernel<<<N_NODES / 8, 256, 0, stream>>>(x, eps, rowptr, csr_src, hp);

    // 3) GEMM1 -> h1p (bf16), persistent grid, B resident in regs
    gemm1_kernel<<<GEMM_GRID, 512, 0, stream>>>(hp, W1, b1, g1, be1, m1, v1, h1p);

    // 4) GEMM2 -> out (f32)
    gemm2_kernel<<<GEMM_GRID, 512, 0, stream>>>(h1p, W2, b2, g2, be2, m2, v2, (float*)d_out);
}

// Round 8
// 239.728 us; speedup vs baseline: 12.9872x; 1.6607x over previous
//
#include <hip/hip_runtime.h>

#define N_NODES 100000
#define DIM     128
#define HID     256
#define BN_EPS  1e-5f
#define TILES   3125          // N_NODES / 32
#define GEMM_GRID 256
#define BK_BITS 9             // 512 dst-nodes per bucket
#define NBK     196           // ceil(100000/512)
#define BKCAP   12288         // avg 8163/bucket, +5 sigma ~ 8613; 1.5x margin
#define EPB     4096          // edges per binscatter block

typedef short        short8 __attribute__((ext_vector_type(8)));
typedef float        f32x4  __attribute__((ext_vector_type(4)));
typedef unsigned int u32x4  __attribute__((ext_vector_type(4)));

static __device__ __forceinline__ unsigned int f2bf(float f) {
    unsigned int u = __builtin_bit_cast(unsigned int, f);
    return (u + 0x7fffu + ((u >> 16) & 1u)) >> 16;   // RNE
}
static __device__ __forceinline__ float bf2f(unsigned int h) {
    unsigned int u = h << 16;
    return __builtin_bit_cast(float, u);
}
static __device__ __forceinline__ unsigned int packsplit(float f) {
    unsigned int hi = f2bf(f);
    unsigned int lo = f2bf(f - bf2f(hi)) & 0xFFFFu;
    return (hi << 16) | lo;
}
static __device__ __forceinline__ f32x4 mfma16(short8 a, short8 b, f32x4 c) {
    return __builtin_amdgcn_mfma_f32_16x16x32_bf16(a, b, c, 0, 0, 0);
}

// ---------------- Binning pass 1: block-local count -> chunk claim -> dense pair write ----------------
__global__ __launch_bounds__(256) void binscatter_kernel(
    const int* __restrict__ src, const int* __restrict__ dst,
    int* __restrict__ cursor, uint2* __restrict__ pairs, int nE) {
    __shared__ int cnt[NBK];
    __shared__ int gbase[NBK];
    int t = threadIdx.x;
    for (int i = t; i < NBK; i += 256) cnt[i] = 0;
    __syncthreads();
    int e0 = blockIdx.x * EPB;
    int n = min(EPB, nE - e0);
    int d[16];
#pragma unroll
    for (int k = 0; k < 16; ++k) {
        int idx = t + k * 256;
        if (idx < n) {
            d[k] = dst[e0 + idx];
            atomicAdd(&cnt[d[k] >> BK_BITS], 1);
        }
    }
    __syncthreads();
    for (int i = t; i < NBK; i += 256) {
        int c = cnt[i];
        gbase[i] = c ? atomicAdd(&cursor[i], c) : 0;
    }
    __syncthreads();
    for (int i = t; i < NBK; i += 256) cnt[i] = 0;
    __syncthreads();
#pragma unroll
    for (int k = 0; k < 16; ++k) {
        int idx = t + k * 256;
        if (idx < n) {
            int b = d[k] >> BK_BITS;
            int r = atomicAdd(&cnt[b], 1);
            pairs[(long long)b * BKCAP + gbase[b] + r] =
                make_uint2((unsigned)src[e0 + idx], (unsigned)d[k]);
        }
    }
}

// exclusive scan of NBK bucket counts (single block)
__global__ __launch_bounds__(256) void bscan_kernel(const int* __restrict__ cursor,
                                                    int* __restrict__ bbase) {
    __shared__ int tmp[256];
    int t = threadIdx.x;
    int v = (t < NBK) ? cursor[t] : 0;
    tmp[t] = v;
    __syncthreads();
    for (int s = 1; s < 256; s <<= 1) {
        int a = (t >= s) ? tmp[t - s] : 0;
        __syncthreads();
        tmp[t] += a;
        __syncthreads();
    }
    if (t < NBK) bbase[t] = tmp[t] - v;
}

// ---------------- Binning pass 2: per-bucket rowptr + dense csr fill (no global atomics) ----------------
__global__ __launch_bounds__(512) void bucket_fill_kernel(
    const uint2* __restrict__ pairs, const int* __restrict__ cursor,
    const int* __restrict__ bbase, int* __restrict__ rowptr, int* __restrict__ csr_src) {
    __shared__ int cnt[512];
    __shared__ int off[512];
    int b = blockIdx.x;
    int t = threadIdx.x;
    int nd0 = b << BK_BITS;
    int nn = min(512, N_NODES - nd0);
    int m = cursor[b];
    int base = bbase[b];
    const uint2* bp = pairs + (long long)b * BKCAP;
    cnt[t] = 0;
    __syncthreads();
    for (int e = t; e < m; e += 512)
        atomicAdd(&cnt[bp[e].y & 511], 1);
    __syncthreads();
    int v = cnt[t];
    off[t] = v;
    __syncthreads();
    for (int s = 1; s < 512; s <<= 1) {          // Hillis-Steele inclusive scan
        int a = (t >= s) ? off[t - s] : 0;
        __syncthreads();
        off[t] += a;
        __syncthreads();
    }
    int excl = off[t] - v;
    __syncthreads();
    off[t] = excl;                                // own slot only
    if (t < nn) rowptr[nd0 + t] = base + excl;
    if (b == NBK - 1 && t == 0) rowptr[N_NODES] = base + m;
    cnt[t] = 0;
    __syncthreads();
    for (int e = t; e < m; e += 512) {
        uint2 p = bp[e];
        int li = p.y & 511;
        int r = atomicAdd(&cnt[li], 1);
        csr_src[base + off[li] + r] = (int)p.x;   // dense 33KB window per bucket
    }
}

// ---------------- Gather-sum + pack: 32 lanes per node, float4/lane ----------------
__global__ __launch_bounds__(256) void gather_pack_kernel(
    const float* __restrict__ x, const float* __restrict__ epsp,
    const int* __restrict__ rowptr, const int* __restrict__ csr_src,
    unsigned int* __restrict__ hp) {
    int node = blockIdx.x * 8 + (threadIdx.x >> 5);
    int lane = threadIdx.x & 31;
    const float4* xp = (const float4*)x;
    int beg = rowptr[node], end = rowptr[node + 1];
    float4 a0 = {0.f,0.f,0.f,0.f}, a1 = {0.f,0.f,0.f,0.f};
    float4 a2 = {0.f,0.f,0.f,0.f}, a3 = {0.f,0.f,0.f,0.f};
#define ACC4(A, V) { A.x += V.x; A.y += V.y; A.z += V.z; A.w += V.w; }
    int j = beg;
    for (; j + 4 <= end; j += 4) {
        int s0 = csr_src[j], s1 = csr_src[j+1], s2 = csr_src[j+2], s3 = csr_src[j+3];
        float4 v0 = xp[s0 * 32 + lane];
        float4 v1 = xp[s1 * 32 + lane];
        float4 v2 = xp[s2 * 32 + lane];
        float4 v3 = xp[s3 * 32 + lane];
        ACC4(a0, v0); ACC4(a1, v1); ACC4(a2, v2); ACC4(a3, v3);
    }
    for (; j < end; ++j) {
        int s = csr_src[j];
        float4 v = xp[s * 32 + lane];
        ACC4(a0, v);
    }
#undef ACC4
    float sc = 1.f + epsp[0];
    float4 xv = xp[node * 32 + lane];
    u32x4 pk;
    pk[0] = packsplit(fmaf(sc, xv.x, a0.x + a1.x + a2.x + a3.x));
    pk[1] = packsplit(fmaf(sc, xv.y, a0.y + a1.y + a2.y + a3.y));
    pk[2] = packsplit(fmaf(sc, xv.z, a0.z + a1.z + a2.z + a3.z));
    pk[3] = packsplit(fmaf(sc, xv.w, a0.w + a1.w + a2.w + a3.w));
    ((u32x4*)hp)[node * 32 + lane] = pk;
}

// ---------------- GEMM1 (persistent, B in regs): h1p = relu(bn1(hp @ W1)) ----------------
__global__ __launch_bounds__(512, 2) void gemm1_kernel(
    const unsigned int* __restrict__ hp, const float* __restrict__ W1,
    const float* __restrict__ b1, const float* __restrict__ g1,
    const float* __restrict__ be1, const float* __restrict__ m1,
    const float* __restrict__ v1, unsigned short* __restrict__ h1p) {
    int t = threadIdx.x;
    int w = t >> 6, l = t & 63;
    int l15 = l & 15, q = l >> 4;
    int cg = w & 3, mg = w >> 2;

    short8 B1[4][4];
    float s1v[4], sh1v[4];
#pragma unroll
    for (int nt = 0; nt < 4; ++nt) {
        int col = 64 * cg + 16 * nt + l15;
#pragma unroll
        for (int ks = 0; ks < 4; ++ks) {
            short8 bh;
#pragma unroll
            for (int i = 0; i < 8; ++i)
                bh[i] = (short)f2bf(W1[(32 * ks + 8 * q + i) * HID + col]);
            B1[nt][ks] = bh;
        }
        float sc = g1[col] * rsqrtf(v1[col] + BN_EPS);
        s1v[nt] = sc;
        sh1v[nt] = (b1[col] - m1[col]) * sc + be1[col];
    }

    for (int tile = blockIdx.x; tile < TILES; tile += GEMM_GRID) {
        int row0 = tile * 32;
        int row = row0 + 16 * mg + l15;
        const u32x4* ap = (const u32x4*)hp + row * 32;
        short8 Ah[4], Al[4];
#pragma unroll
        for (int ks = 0; ks < 4; ++ks) {
            u32x4 p0 = ap[8 * ks + 2 * q];
            u32x4 p1 = ap[8 * ks + 2 * q + 1];
            u32x4 hw, lw;
            hw[0] = (p0[0] >> 16) | (p0[1] & 0xFFFF0000u);
            hw[1] = (p0[2] >> 16) | (p0[3] & 0xFFFF0000u);
            hw[2] = (p1[0] >> 16) | (p1[1] & 0xFFFF0000u);
            hw[3] = (p1[2] >> 16) | (p1[3] & 0xFFFF0000u);
            lw[0] = (p0[0] & 0xFFFFu) | (p0[1] << 16);
            lw[1] = (p0[2] & 0xFFFFu) | (p0[3] << 16);
            lw[2] = (p1[0] & 0xFFFFu) | (p1[1] << 16);
            lw[3] = (p1[2] & 0xFFFFu) | (p1[3] << 16);
            Ah[ks] = __builtin_bit_cast(short8, hw);
            Al[ks] = __builtin_bit_cast(short8, lw);
        }
        f32x4 acc[4];
#pragma unroll
        for (int nt = 0; nt < 4; ++nt) acc[nt] = (f32x4)(0.f);
#pragma unroll
        for (int nt = 0; nt < 4; ++nt)
#pragma unroll
            for (int ks = 0; ks < 4; ++ks) {
                acc[nt] = mfma16(Ah[ks], B1[nt][ks], acc[nt]);
                acc[nt] = mfma16(Al[ks], B1[nt][ks], acc[nt]);
            }
#pragma unroll
        for (int nt = 0; nt < 4; ++nt) {
            int col = 64 * cg + 16 * nt + l15;
#pragma unroll
            for (int reg = 0; reg < 4; ++reg) {
                int orow = row0 + 16 * mg + 4 * q + reg;
                float vv = fmaxf(0.f, fmaf(acc[nt][reg], s1v[nt], sh1v[nt]));
                h1p[orow * HID + col] = (unsigned short)f2bf(vv);
            }
        }
    }
}

// ---------------- GEMM2 (persistent, B split in regs): out = relu(bn2(h1 @ W2)) ----------------
__global__ __launch_bounds__(512, 2) void gemm2_kernel(
    const unsigned short* __restrict__ h1p, const float* __restrict__ W2,
    const float* __restrict__ b2, const float* __restrict__ g2,
    const float* __restrict__ be2, const float* __restrict__ m2,
    const float* __restrict__ v2, float* __restrict__ out) {
    int t = threadIdx.x;
    int w = t >> 6, l = t & 63;
    int l15 = l & 15, q = l >> 4;
    int cg = w & 3, mg = w >> 2;

    short8 B2h[2][8], B2l[2][8];
    float s2v[2], sh2v[2];
#pragma unroll
    for (int nt = 0; nt < 2; ++nt) {
        int col = 32 * cg + 16 * nt + l15;
#pragma unroll
        for (int ks = 0; ks < 8; ++ks) {
            short8 bh, bl;
#pragma unroll
            for (int i = 0; i < 8; ++i) {
                float wv = W2[(32 * ks + 8 * q + i) * DIM + col];
                unsigned int hv = f2bf(wv);
                bh[i] = (short)hv;
                bl[i] = (short)f2bf(wv - bf2f(hv));
            }
            B2h[nt][ks] = bh; B2l[nt][ks] = bl;
        }
        float sc = g2[col] * rsqrtf(v2[col] + BN_EPS);
        s2v[nt] = sc;
        sh2v[nt] = (b2[col] - m2[col]) * sc + be2[col];
    }

    for (int tile = blockIdx.x; tile < TILES; tile += GEMM_GRID) {
        int row0 = tile * 32;
        int row = row0 + 16 * mg + l15;
        const short8* a2p = (const short8*)(h1p + row * HID);
        short8 A2[8];
#pragma unroll
        for (int ks = 0; ks < 8; ++ks) A2[ks] = a2p[4 * ks + q];
        f32x4 acc[2];
        acc[0] = (f32x4)(0.f); acc[1] = (f32x4)(0.f);
#pragma unroll
        for (int nt = 0; nt < 2; ++nt)
#pragma unroll
            for (int ks = 0; ks < 8; ++ks) {
                acc[nt] = mfma16(A2[ks], B2h[nt][ks], acc[nt]);
                acc[nt] = mfma16(A2[ks], B2l[nt][ks], acc[nt]);
            }
#pragma unroll
        for (int nt = 0; nt < 2; ++nt) {
            int col = 32 * cg + 16 * nt + l15;
#pragma unroll
            for (int reg = 0; reg < 4; ++reg) {
                int orow = row0 + 16 * mg + 4 * q + reg;
                out[orow * DIM + col] = fmaxf(0.f, fmaf(acc[nt][reg], s2v[nt], sh2v[nt]));
            }
        }
    }
}

extern "C" void kernel_launch(void* const* d_in, const int* in_sizes, int n_in,
                              void* d_out, int out_size, void* d_ws, size_t ws_size,
                              hipStream_t stream) {
    const float* x   = (const float*)d_in[0];
    const float* eps = (const float*)d_in[1];
    const float* W1  = (const float*)d_in[2];
    const float* b1  = (const float*)d_in[3];
    const float* g1  = (const float*)d_in[4];
    const float* be1 = (const float*)d_in[5];
    const float* m1  = (const float*)d_in[6];
    const float* v1  = (const float*)d_in[7];
    const float* W2  = (const float*)d_in[8];
    const float* b2  = (const float*)d_in[9];
    const float* g2  = (const float*)d_in[10];
    const float* be2 = (const float*)d_in[11];
    const float* m2  = (const float*)d_in[12];
    const float* v2  = (const float*)d_in[13];
    const int*   ei  = (const int*)d_in[14];
    int nE = in_sizes[14] / 2;
    const int* src = ei;
    const int* dst = ei + nE;

    // ws layout. CSR-build temps + pairs live in [0, 26.1MB); h1p overlaps [0, 51.2MB)
    // but is written (gemm1) only after the last reader of the temps (gather) is done
    // (single-stream serialization). All temps fully rebuilt each call.
    char* ws = (char*)d_ws;
    int*   cursor  = (int*)(ws + 0);          // NBK ints
    int*   bbase   = (int*)(ws + 1024);       // NBK ints
    int*   rowptr  = (int*)(ws + 4096);       // (N+1) ints, ends 404,100
    int*   csr_src = (int*)(ws + 405504);     // nE ints, ends 6,805,504
    uint2* pairs   = (uint2*)(ws + 6806528);  // NBK*BKCAP*8B = 19.3MB, ends 26,074,112
    unsigned short* h1p = (unsigned short*)ws;   // [N][256] bf16 = 51.2 MB

    unsigned int* hp = (unsigned int*)d_out;     // packed h in d_out

    // 1) CSR build via two-level binning
    hipMemsetAsync(cursor, 0, NBK * sizeof(int), stream);
    binscatter_kernel<<<(nE + EPB - 1) / EPB, 256, 0, stream>>>(src, dst, cursor, pairs, nE);
    bscan_kernel<<<1, 256, 0, stream>>>(cursor, bbase);
    bucket_fill_kernel<<<NBK, 512, 0, stream>>>(pairs, cursor, bbase, rowptr, csr_src);

    // 2) gather-sum + split-bf16 pack (writes d_out as u32)
    gather_pack_kernel<<<N_NODES / 8, 256, 0, stream>>>(x, eps, rowptr, csr_src, hp);

    // 3) GEMM1 -> h1p (bf16), persistent grid, B resident in regs
    gemm1_kernel<<<GEMM_GRID, 512, 0, stream>>>(hp, W1, b1, g1, be1, m1, v1, h1p);

    // 4) GEMM2 -> out (f32)
    gemm2_kernel<<<GEMM_GRID, 512, 0, stream>>>(h1p, W2, b2, g2, be2, m2, v2, (float*)d_out);
}

// Round 9
// 179.122 us; speedup vs baseline: 17.3814x; 1.3384x over previous
//
#include <hip/hip_runtime.h>

#define N_NODES 100000
#define DIM     128
#define HID     256
#define BN_EPS  1e-5f
#define TILES   3125          // N_NODES / 32
#define GEMM_GRID 256
#define BK_BITS 9             // 512 dst-nodes per bucket
#define NBK     196           // ceil(100000/512)
#define BKCAP   12288
#define EPB     4096          // edges per binscatter block

typedef _Float16     half4  __attribute__((ext_vector_type(4)));
typedef _Float16     half8  __attribute__((ext_vector_type(8)));
typedef float        f32x4  __attribute__((ext_vector_type(4)));

static __device__ __forceinline__ f32x4 mfma16h(half8 a, half8 b, f32x4 c) {
    return __builtin_amdgcn_mfma_f32_16x16x32_f16(a, b, c, 0, 0, 0);
}

// ---------------- x -> fp16 copy ----------------
__global__ __launch_bounds__(256) void cvt_kernel(const float* __restrict__ x,
                                                  _Float16* __restrict__ x16) {
    int i = blockIdx.x * 256 + threadIdx.x;     // float4 index, 3.2M total
    float4 v = ((const float4*)x)[i];
    half4 o;
    o[0] = (_Float16)v.x; o[1] = (_Float16)v.y;
    o[2] = (_Float16)v.z; o[3] = (_Float16)v.w;
    ((half4*)x16)[i] = o;
}

// ---------------- Binning pass 1 ----------------
__global__ __launch_bounds__(256) void binscatter_kernel(
    const int* __restrict__ src, const int* __restrict__ dst,
    int* __restrict__ cursor, unsigned int* __restrict__ pairs, int nE) {
    __shared__ int cnt[NBK];
    __shared__ int gbase[NBK];
    int t = threadIdx.x;
    for (int i = t; i < NBK; i += 256) cnt[i] = 0;
    __syncthreads();
    int e0 = blockIdx.x * EPB;
    int n = min(EPB, nE - e0);
    int d[16];
#pragma unroll
    for (int k = 0; k < 16; ++k) {
        int idx = t + k * 256;
        if (idx < n) {
            d[k] = dst[e0 + idx];
            atomicAdd(&cnt[d[k] >> BK_BITS], 1);
        }
    }
    __syncthreads();
    for (int i = t; i < NBK; i += 256) {
        int c = cnt[i];
        gbase[i] = c ? atomicAdd(&cursor[i], c) : 0;
    }
    __syncthreads();
    for (int i = t; i < NBK; i += 256) cnt[i] = 0;
    __syncthreads();
#pragma unroll
    for (int k = 0; k < 16; ++k) {
        int idx = t + k * 256;
        if (idx < n) {
            int b = d[k] >> BK_BITS;
            int r = atomicAdd(&cnt[b], 1);
            pairs[(long long)b * BKCAP + gbase[b] + r] =
                ((unsigned)src[e0 + idx] << BK_BITS) | ((unsigned)d[k] & 511u);
        }
    }
}

// exclusive scan of NBK bucket counts
__global__ __launch_bounds__(256) void bscan_kernel(const int* __restrict__ cursor,
                                                    int* __restrict__ bbase) {
    __shared__ int tmp[256];
    int t = threadIdx.x;
    int v = (t < NBK) ? cursor[t] : 0;
    tmp[t] = v;
    __syncthreads();
    for (int s = 1; s < 256; s <<= 1) {
        int a = (t >= s) ? tmp[t - s] : 0;
        __syncthreads();
        tmp[t] += a;
        __syncthreads();
    }
    if (t < NBK) bbase[t] = tmp[t] - v;
}

// ---------------- Binning pass 2 ----------------
__global__ __launch_bounds__(512) void bucket_fill_kernel(
    const unsigned int* __restrict__ pairs, const int* __restrict__ cursor,
    const int* __restrict__ bbase, int* __restrict__ rowptr, int* __restrict__ csr_src) {
    __shared__ int cnt[512];
    __shared__ int off[512];
    int b = blockIdx.x;
    int t = threadIdx.x;
    int nd0 = b << BK_BITS;
    int nn = min(512, N_NODES - nd0);
    int m = cursor[b];
    int base = bbase[b];
    const unsigned int* bp = pairs + (long long)b * BKCAP;
    cnt[t] = 0;
    __syncthreads();
    for (int e = t; e < m; e += 512)
        atomicAdd(&cnt[bp[e] & 511u], 1);
    __syncthreads();
    int v = cnt[t];
    off[t] = v;
    __syncthreads();
    for (int s = 1; s < 512; s <<= 1) {
        int a = (t >= s) ? off[t - s] : 0;
        __syncthreads();
        off[t] += a;
        __syncthreads();
    }
    int excl = off[t] - v;
    __syncthreads();
    off[t] = excl;
    if (t < nn) rowptr[nd0 + t] = base + excl;
    if (b == NBK - 1 && t == 0) rowptr[N_NODES] = base + m;
    cnt[t] = 0;
    __syncthreads();
    for (int e = t; e < m; e += 512) {
        unsigned int p = bp[e];
        int li = p & 511u;
        int r = atomicAdd(&cnt[li], 1);
        csr_src[base + off[li] + r] = (int)(p >> BK_BITS);
    }
}

// ---------------- Gather-sum (fp16 rows) -> h16 ----------------
__global__ __launch_bounds__(256) void gather_pack_kernel(
    const float* __restrict__ x, const _Float16* __restrict__ x16,
    const float* __restrict__ epsp, const int* __restrict__ rowptr,
    const int* __restrict__ csr_src, _Float16* __restrict__ h16) {
    int node = blockIdx.x * 8 + (threadIdx.x >> 5);
    int lane = threadIdx.x & 31;
    const half4* xp = (const half4*)x16;        // row = node*32 + lane (8B/lane)
    int beg = rowptr[node], end = rowptr[node + 1];
    float4 a0 = {0.f,0.f,0.f,0.f}, a1 = {0.f,0.f,0.f,0.f};
    float4 a2 = {0.f,0.f,0.f,0.f}, a3 = {0.f,0.f,0.f,0.f};
#define ACC4(A, V) { A.x += (float)V[0]; A.y += (float)V[1]; A.z += (float)V[2]; A.w += (float)V[3]; }
    int j = beg;
    for (; j + 4 <= end; j += 4) {
        int s0 = csr_src[j], s1 = csr_src[j+1], s2 = csr_src[j+2], s3 = csr_src[j+3];
        half4 v0 = xp[s0 * 32 + lane];
        half4 v1 = xp[s1 * 32 + lane];
        half4 v2 = xp[s2 * 32 + lane];
        half4 v3 = xp[s3 * 32 + lane];
        ACC4(a0, v0); ACC4(a1, v1); ACC4(a2, v2); ACC4(a3, v3);
    }
    for (; j < end; ++j) {
        int s = csr_src[j];
        half4 v = xp[s * 32 + lane];
        ACC4(a0, v);
    }
#undef ACC4
    float sc = 1.f + epsp[0];
    float4 xv = ((const float4*)x)[node * 32 + lane];   // self term full precision
    half4 o;
    o[0] = (_Float16)fmaf(sc, xv.x, a0.x + a1.x + a2.x + a3.x);
    o[1] = (_Float16)fmaf(sc, xv.y, a0.y + a1.y + a2.y + a3.y);
    o[2] = (_Float16)fmaf(sc, xv.z, a0.z + a1.z + a2.z + a3.z);
    o[3] = (_Float16)fmaf(sc, xv.w, a0.w + a1.w + a2.w + a3.w);
    ((half4*)h16)[node * 32 + lane] = o;
}

// ---------------- GEMM1 (persistent, B split-fp16 in regs): h1p = relu(bn1(h16 @ W1)) ----------------
__global__ __launch_bounds__(512, 2) void gemm1_kernel(
    const _Float16* __restrict__ h16, const float* __restrict__ W1,
    const float* __restrict__ b1, const float* __restrict__ g1,
    const float* __restrict__ be1, const float* __restrict__ m1,
    const float* __restrict__ v1, _Float16* __restrict__ h1p) {
    int t = threadIdx.x;
    int w = t >> 6, l = t & 63;
    int l15 = l & 15, q = l >> 4;
    int cg = w & 3, mg = w >> 2;

    half8 B1h[4][4], B1l[4][4];
    float s1v[4], sh1v[4];
#pragma unroll
    for (int nt = 0; nt < 4; ++nt) {
        int col = 64 * cg + 16 * nt + l15;
#pragma unroll
        for (int ks = 0; ks < 4; ++ks) {
            half8 bh, bl;
#pragma unroll
            for (int i = 0; i < 8; ++i) {
                float wv = W1[(32 * ks + 8 * q + i) * HID + col];
                _Float16 hh = (_Float16)wv;
                bh[i] = hh;
                bl[i] = (_Float16)(wv - (float)hh);
            }
            B1h[nt][ks] = bh; B1l[nt][ks] = bl;
        }
        float sc = g1[col] * rsqrtf(v1[col] + BN_EPS);
        s1v[nt] = sc;
        sh1v[nt] = (b1[col] - m1[col]) * sc + be1[col];
    }

    for (int tile = blockIdx.x; tile < TILES; tile += GEMM_GRID) {
        int row0 = tile * 32;
        int row = row0 + 16 * mg + l15;
        const _Float16* arow = h16 + (long long)row * DIM;
        half8 A[4];
#pragma unroll
        for (int ks = 0; ks < 4; ++ks) A[ks] = *(const half8*)(arow + 32 * ks + 8 * q);
        f32x4 acc[4];
#pragma unroll
        for (int nt = 0; nt < 4; ++nt) acc[nt] = (f32x4)(0.f);
#pragma unroll
        for (int nt = 0; nt < 4; ++nt)
#pragma unroll
            for (int ks = 0; ks < 4; ++ks) {
                acc[nt] = mfma16h(A[ks], B1h[nt][ks], acc[nt]);
                acc[nt] = mfma16h(A[ks], B1l[nt][ks], acc[nt]);
            }
#pragma unroll
        for (int nt = 0; nt < 4; ++nt) {
            int col = 64 * cg + 16 * nt + l15;
#pragma unroll
            for (int reg = 0; reg < 4; ++reg) {
                int orow = row0 + 16 * mg + 4 * q + reg;
                float vv = fmaxf(0.f, fmaf(acc[nt][reg], s1v[nt], sh1v[nt]));
                h1p[(long long)orow * HID + col] = (_Float16)vv;
            }
        }
    }
}

// ---------------- GEMM2 (persistent, B split-fp16 in regs): out = relu(bn2(h1p @ W2)) ----------------
__global__ __launch_bounds__(512, 2) void gemm2_kernel(
    const _Float16* __restrict__ h1p, const float* __restrict__ W2,
    const float* __restrict__ b2, const float* __restrict__ g2,
    const float* __restrict__ be2, const float* __restrict__ m2,
    const float* __restrict__ v2, float* __restrict__ out) {
    int t = threadIdx.x;
    int w = t >> 6, l = t & 63;
    int l15 = l & 15, q = l >> 4;
    int cg = w & 3, mg = w >> 2;

    half8 B2h[2][8], B2l[2][8];
    float s2v[2], sh2v[2];
#pragma unroll
    for (int nt = 0; nt < 2; ++nt) {
        int col = 32 * cg + 16 * nt + l15;
#pragma unroll
        for (int ks = 0; ks < 8; ++ks) {
            half8 bh, bl;
#pragma unroll
            for (int i = 0; i < 8; ++i) {
                float wv = W2[(32 * ks + 8 * q + i) * DIM + col];
                _Float16 hh = (_Float16)wv;
                bh[i] = hh;
                bl[i] = (_Float16)(wv - (float)hh);
            }
            B2h[nt][ks] = bh; B2l[nt][ks] = bl;
        }
        float sc = g2[col] * rsqrtf(v2[col] + BN_EPS);
        s2v[nt] = sc;
        sh2v[nt] = (b2[col] - m2[col]) * sc + be2[col];
    }

    for (int tile = blockIdx.x; tile < TILES; tile += GEMM_GRID) {
        int row0 = tile * 32;
        int row = row0 + 16 * mg + l15;
        const _Float16* arow = h1p + (long long)row * HID;
        half8 A2[8];
#pragma unroll
        for (int ks = 0; ks < 8; ++ks) A2[ks] = *(const half8*)(arow + 32 * ks + 8 * q);
        f32x4 acc[2];
        acc[0] = (f32x4)(0.f); acc[1] = (f32x4)(0.f);
#pragma unroll
        for (int nt = 0; nt < 2; ++nt)
#pragma unroll
            for (int ks = 0; ks < 8; ++ks) {
                acc[nt] = mfma16h(A2[ks], B2h[nt][ks], acc[nt]);
                acc[nt] = mfma16h(A2[ks], B2l[nt][ks], acc[nt]);
            }
#pragma unroll
        for (int nt = 0; nt < 2; ++nt) {
            int col = 32 * cg + 16 * nt + l15;
#pragma unroll
            for (int reg = 0; reg < 4; ++reg) {
                int orow = row0 + 16 * mg + 4 * q + reg;
                out[(long long)orow * DIM + col] = fmaxf(0.f, fmaf(acc[nt][reg], s2v[nt], sh2v[nt]));
            }
        }
    }
}

extern "C" void kernel_launch(void* const* d_in, const int* in_sizes, int n_in,
                              void* d_out, int out_size, void* d_ws, size_t ws_size,
                              hipStream_t stream) {
    const float* x   = (const float*)d_in[0];
    const float* eps = (const float*)d_in[1];
    const float* W1  = (const float*)d_in[2];
    const float* b1  = (const float*)d_in[3];
    const float* g1  = (const float*)d_in[4];
    const float* be1 = (const float*)d_in[5];
    const float* m1  = (const float*)d_in[6];
    const float* v1  = (const float*)d_in[7];
    const float* W2  = (const float*)d_in[8];
    const float* b2  = (const float*)d_in[9];
    const float* g2  = (const float*)d_in[10];
    const float* be2 = (const float*)d_in[11];
    const float* m2  = (const float*)d_in[12];
    const float* v2  = (const float*)d_in[13];
    const int*   ei  = (const int*)d_in[14];
    int nE = in_sizes[14] / 2;
    const int* src = ei;
    const int* dst = ei + nE;

    // ws layout. All regions < 51.2MB. h1p [0,51.2MB) overwrites the CSR temps/x16,
    // which are dead once gather completes (single-stream ordering).
    char* ws = (char*)d_ws;
    int*          cursor  = (int*)(ws + 0);           // NBK ints
    int*          bbase   = (int*)(ws + 1024);        // NBK ints
    int*          rowptr  = (int*)(ws + 4096);        // (N+1) ints -> ends 404,100
    int*          csr_src = (int*)(ws + 405504);      // nE ints -> ends 6,805,504
    unsigned int* pairs   = (unsigned int*)(ws + 6806528);  // 9.63MB -> ends 16,440,320
    _Float16*     x16     = (_Float16*)(ws + 16441344);     // 25.6MB -> ends 42,041,344
    _Float16*     h1p     = (_Float16*)ws;            // [N][256] fp16 = 51.2MB

    _Float16* h16 = (_Float16*)d_out;                 // [N][128] fp16, first 25.6MB of d_out

    // 0) x -> fp16 (region disjoint from all CSR temps)
    cvt_kernel<<<N_NODES * DIM / 4 / 256, 256, 0, stream>>>(x, x16);

    // 1) CSR build via two-level binning
    hipMemsetAsync(cursor, 0, NBK * sizeof(int), stream);
    binscatter_kernel<<<(nE + EPB - 1) / EPB, 256, 0, stream>>>(src, dst, cursor, pairs, nE);
    bscan_kernel<<<1, 256, 0, stream>>>(cursor, bbase);
    bucket_fill_kernel<<<NBK, 512, 0, stream>>>(pairs, cursor, bbase, rowptr, csr_src);

    // 2) gather-sum (fp16 neighbor rows, fp32 self) -> h16 in d_out
    gather_pack_kernel<<<N_NODES / 8, 256, 0, stream>>>(x, x16, eps, rowptr, csr_src, h16);

    // 3) GEMM1 -> h1p (fp16)
    gemm1_kernel<<<GEMM_GRID, 512, 0, stream>>>(h16, W1, b1, g1, be1, m1, v1, h1p);

    // 4) GEMM2 -> out (fp32, overwrites all of d_out)
    gemm2_kernel<<<GEMM_GRID, 512, 0, stream>>>(h1p, W2, b2, g2, be2, m2, v2, (float*)d_out);
}

// Round 10
// 153.740 us; speedup vs baseline: 20.2511x; 1.1651x over previous
//
#include <hip/hip_runtime.h>

#define N_NODES 100000
#define DIM     128
#define HID     256
#define BN_EPS  1e-5f
#define TILES   3125          // N_NODES / 32
#define GEMM_GRID 256
#define BK_BITS 9             // 512 dst-nodes per bucket
#define NBK     196           // ceil(100000/512)
#define BKCAP   12288
#define EPB     4096          // edges per binscatter block
#define BIN_BLOCKS 391        // ceil(1.6M/4096)
#define CVT_BLOCKS 3125       // 3.2M float4 / 1024 per block

typedef _Float16     half8  __attribute__((ext_vector_type(8)));
typedef float        f32x4  __attribute__((ext_vector_type(4)));

static __device__ __forceinline__ f32x4 mfma16h(half8 a, half8 b, f32x4 c) {
    return __builtin_amdgcn_mfma_f32_16x16x32_f16(a, b, c, 0, 0, 0);
}

// ---------------- Fused: binscatter (blocks 0..390) + x->fp16 cvt (blocks 391..3515) ----------------
__global__ __launch_bounds__(256) void bin_cvt_kernel(
    const int* __restrict__ src, const int* __restrict__ dst,
    int* __restrict__ cursor, unsigned int* __restrict__ pairs, int nE,
    const float* __restrict__ x, _Float16* __restrict__ x16) {
    int t = threadIdx.x;
    if (blockIdx.x >= BIN_BLOCKS) {
        // ---- cvt part: 4 float4 per thread, coalesced per k-iteration ----
        int bc = blockIdx.x - BIN_BLOCKS;
#pragma unroll
        for (int k = 0; k < 4; ++k) {
            int i = bc * 1024 + k * 256 + t;
            float4 v = ((const float4*)x)[i];
            half8 o8;   // write as 8B: use half of it... simpler: 4 halves
            _Float16 h0 = (_Float16)v.x, h1 = (_Float16)v.y,
                     h2 = (_Float16)v.z, h3 = (_Float16)v.w;
            unsigned long long pk =
                (unsigned long long)__builtin_bit_cast(unsigned short, h0)
              | ((unsigned long long)__builtin_bit_cast(unsigned short, h1) << 16)
              | ((unsigned long long)__builtin_bit_cast(unsigned short, h2) << 32)
              | ((unsigned long long)__builtin_bit_cast(unsigned short, h3) << 48);
            ((unsigned long long*)x16)[i] = pk;
            (void)o8;
        }
        return;
    }
    // ---- binscatter part ----
    __shared__ int cnt[NBK];
    __shared__ int gbase[NBK];
    for (int i = t; i < NBK; i += 256) cnt[i] = 0;
    __syncthreads();
    int e0 = blockIdx.x * EPB;
    int n = min(EPB, nE - e0);
    int d[16];
#pragma unroll
    for (int k = 0; k < 16; ++k) {
        int idx = t + k * 256;
        if (idx < n) {
            d[k] = dst[e0 + idx];
            atomicAdd(&cnt[d[k] >> BK_BITS], 1);
        }
    }
    __syncthreads();
    for (int i = t; i < NBK; i += 256) {
        int c = cnt[i];
        gbase[i] = c ? atomicAdd(&cursor[i], c) : 0;
    }
    __syncthreads();
    for (int i = t; i < NBK; i += 256) cnt[i] = 0;
    __syncthreads();
#pragma unroll
    for (int k = 0; k < 16; ++k) {
        int idx = t + k * 256;
        if (idx < n) {
            int b = d[k] >> BK_BITS;
            int r = atomicAdd(&cnt[b], 1);
            pairs[(long long)b * BKCAP + gbase[b] + r] =
                ((unsigned)src[e0 + idx] << BK_BITS) | ((unsigned)d[k] & 511u);
        }
    }
}

// ---------------- Binning pass 2 (bscan folded in) ----------------
__global__ __launch_bounds__(512) void bucket_fill_kernel(
    const unsigned int* __restrict__ pairs, const int* __restrict__ cursor,
    int* __restrict__ rowptr, int* __restrict__ csr_src) {
    __shared__ int cnt[512];
    __shared__ int off[512];
    __shared__ int stmp[256];
    __shared__ int s_base;
    int b = blockIdx.x;
    int t = threadIdx.x;
    // fold bscan: inclusive scan of cursor[0..NBK) in stmp, base = incl[b]-cursor[b]
    if (t < 256) stmp[t] = (t < NBK) ? cursor[t] : 0;
    __syncthreads();
    for (int s = 1; s < 256; s <<= 1) {
        int a = (t >= s && t < 256) ? stmp[t - s] : 0;
        __syncthreads();
        if (t < 256) stmp[t] += a;
        __syncthreads();
    }
    if (t == 0) s_base = stmp[b] - cursor[b];
    __syncthreads();
    int base = s_base;
    int m = cursor[b];
    int nd0 = b << BK_BITS;
    int nn = min(512, N_NODES - nd0);
    const unsigned int* bp = pairs + (long long)b * BKCAP;
    cnt[t] = 0;
    __syncthreads();
    for (int e = t; e < m; e += 512)
        atomicAdd(&cnt[bp[e] & 511u], 1);
    __syncthreads();
    int v = cnt[t];
    off[t] = v;
    __syncthreads();
    for (int s = 1; s < 512; s <<= 1) {
        int a = (t >= s) ? off[t - s] : 0;
        __syncthreads();
        off[t] += a;
        __syncthreads();
    }
    int excl = off[t] - v;
    __syncthreads();
    off[t] = excl;
    if (t < nn) rowptr[nd0 + t] = base + excl;
    if (b == NBK - 1 && t == 0) rowptr[N_NODES] = base + m;
    cnt[t] = 0;
    __syncthreads();
    for (int e = t; e < m; e += 512) {
        unsigned int p = bp[e];
        int li = p & 511u;
        int r = atomicAdd(&cnt[li], 1);
        csr_src[base + off[li] + r] = (int)(p >> BK_BITS);
    }
}

// ---------------- Gather-sum: 16 lanes/node, half8 (16B) loads, 4-deep MLP ----------------
__global__ __launch_bounds__(256) void gather_kernel(
    const float* __restrict__ x, const _Float16* __restrict__ x16,
    const float* __restrict__ epsp, const int* __restrict__ rowptr,
    const int* __restrict__ csr_src, _Float16* __restrict__ h16) {
    int node = blockIdx.x * 16 + (threadIdx.x >> 4);   // 6250 blocks x 16 nodes
    int lane = threadIdx.x & 15;
    const half8* xp = (const half8*)x16;               // row = node*16 + lane
    int beg = rowptr[node], end = rowptr[node + 1];
    float s0[8] = {0,0,0,0,0,0,0,0}, s1[8] = {0,0,0,0,0,0,0,0};
    int j = beg;
    for (; j + 4 <= end; j += 4) {
        int n0 = csr_src[j], n1 = csr_src[j+1], n2 = csr_src[j+2], n3 = csr_src[j+3];
        half8 v0 = xp[n0 * 16 + lane];
        half8 v1 = xp[n1 * 16 + lane];
        half8 v2 = xp[n2 * 16 + lane];
        half8 v3 = xp[n3 * 16 + lane];
#pragma unroll
        for (int i = 0; i < 8; ++i) {
            s0[i] += (float)v0[i]; s1[i] += (float)v1[i];
            s0[i] += (float)v2[i]; s1[i] += (float)v3[i];
        }
    }
    for (; j < end; ++j) {
        half8 v = xp[csr_src[j] * 16 + lane];
#pragma unroll
        for (int i = 0; i < 8; ++i) s0[i] += (float)v[i];
    }
    float sc = 1.f + epsp[0];
    float4 xa = ((const float4*)x)[node * 32 + lane * 2];
    float4 xb = ((const float4*)x)[node * 32 + lane * 2 + 1];
    half8 o;
    o[0] = (_Float16)fmaf(sc, xa.x, s0[0] + s1[0]);
    o[1] = (_Float16)fmaf(sc, xa.y, s0[1] + s1[1]);
    o[2] = (_Float16)fmaf(sc, xa.z, s0[2] + s1[2]);
    o[3] = (_Float16)fmaf(sc, xa.w, s0[3] + s1[3]);
    o[4] = (_Float16)fmaf(sc, xb.x, s0[4] + s1[4]);
    o[5] = (_Float16)fmaf(sc, xb.y, s0[5] + s1[5]);
    o[6] = (_Float16)fmaf(sc, xb.z, s0[6] + s1[6]);
    o[7] = (_Float16)fmaf(sc, xb.w, s0[7] + s1[7]);
    ((half8*)h16)[node * 16 + lane] = o;
}

// ---------------- Fused MLP (persistent, both B's in regs, h1 tile in swizzled LDS) ----------------
// 512 thr = 8 waves: mg=w>>2 (16-row half), cg=w&3 (col quarter).
// L1: cols 64cg+16nt+l15 (nt<4). L2: cols 32cg+16nt+l15 (nt<2).
__global__ __launch_bounds__(512, 2) void mlp_fused_kernel(
    const _Float16* __restrict__ h16,
    const float* __restrict__ W1, const float* __restrict__ b1,
    const float* __restrict__ g1, const float* __restrict__ be1,
    const float* __restrict__ m1, const float* __restrict__ v1,
    const float* __restrict__ W2, const float* __restrict__ b2,
    const float* __restrict__ g2, const float* __restrict__ be2,
    const float* __restrict__ m2, const float* __restrict__ v2,
    float* __restrict__ out) {
    __shared__ _Float16 sh1[32 * HID];   // 16 KB, XOR-swizzled (16B granule ^ (row&7))
    int t = threadIdx.x;
    int w = t >> 6, l = t & 63;
    int l15 = l & 15, q = l >> 4;
    int cg = w & 3, mg = w >> 2;

    // B1 (fp16 only) + BN1 fold
    half8 B1[4][4];
    float s1v[4], sh1v[4];
#pragma unroll
    for (int nt = 0; nt < 4; ++nt) {
        int col = 64 * cg + 16 * nt + l15;
#pragma unroll
        for (int ks = 0; ks < 4; ++ks) {
            half8 bh;
#pragma unroll
            for (int i = 0; i < 8; ++i)
                bh[i] = (_Float16)W1[(32 * ks + 8 * q + i) * HID + col];
            B1[nt][ks] = bh;
        }
        float sc = g1[col] * rsqrtf(v1[col] + BN_EPS);
        s1v[nt] = sc;
        sh1v[nt] = (b1[col] - m1[col]) * sc + be1[col];
    }
    // B2 (fp16 only) + BN2 fold
    half8 B2[2][8];
    float s2v[2], sh2v[2];
#pragma unroll
    for (int nt = 0; nt < 2; ++nt) {
        int col = 32 * cg + 16 * nt + l15;
#pragma unroll
        for (int ks = 0; ks < 8; ++ks) {
            half8 bh;
#pragma unroll
            for (int i = 0; i < 8; ++i)
                bh[i] = (_Float16)W2[(32 * ks + 8 * q + i) * DIM + col];
            B2[nt][ks] = bh;
        }
        float sc = g2[col] * rsqrtf(v2[col] + BN_EPS);
        s2v[nt] = sc;
        sh2v[nt] = (b2[col] - m2[col]) * sc + be2[col];
    }

    for (int tile = blockIdx.x; tile < TILES; tile += GEMM_GRID) {
        int row0 = tile * 32;
        // ---- layer 1 ----
        const _Float16* arow = h16 + (long long)(row0 + 16 * mg + l15) * DIM;
        half8 A[4];
#pragma unroll
        for (int ks = 0; ks < 4; ++ks) A[ks] = *(const half8*)(arow + 32 * ks + 8 * q);
        f32x4 acc[4];
#pragma unroll
        for (int nt = 0; nt < 4; ++nt) acc[nt] = (f32x4)(0.f);
#pragma unroll
        for (int nt = 0; nt < 4; ++nt)
#pragma unroll
            for (int ks = 0; ks < 4; ++ks)
                acc[nt] = mfma16h(A[ks], B1[nt][ks], acc[nt]);
        // BN1+ReLU -> swizzled LDS (half-index ^ = (row&7)<<3)
#pragma unroll
        for (int nt = 0; nt < 4; ++nt) {
            int col = 64 * cg + 16 * nt + l15;
#pragma unroll
            for (int reg = 0; reg < 4; ++reg) {
                int row = 16 * mg + 4 * q + reg;
                float vv = fmaxf(0.f, fmaf(acc[nt][reg], s1v[nt], sh1v[nt]));
                sh1[row * HID + (col ^ ((row & 7) << 3))] = (_Float16)vv;
            }
        }
        __syncthreads();
        // ---- layer 2: A2 from swizzled LDS ----
        half8 A2[8];
        {
            int row = 16 * mg + l15;
            int sx = (row & 7) << 3;
#pragma unroll
            for (int ks = 0; ks < 8; ++ks)
                A2[ks] = *(const half8*)&sh1[row * HID + ((32 * ks + 8 * q) ^ sx)];
        }
        __syncthreads();   // release sh1 for next tile once all reads issued
        f32x4 acc2[2];
        acc2[0] = (f32x4)(0.f); acc2[1] = (f32x4)(0.f);
#pragma unroll
        for (int nt = 0; nt < 2; ++nt)
#pragma unroll
            for (int ks = 0; ks < 8; ++ks)
                acc2[nt] = mfma16h(A2[ks], B2[nt][ks], acc2[nt]);
#pragma unroll
        for (int nt = 0; nt < 2; ++nt) {
            int col = 32 * cg + 16 * nt + l15;
#pragma unroll
            for (int reg = 0; reg < 4; ++reg) {
                int orow = row0 + 16 * mg + 4 * q + reg;
                out[(long long)orow * DIM + col] =
                    fmaxf(0.f, fmaf(acc2[nt][reg], s2v[nt], sh2v[nt]));
            }
        }
    }
}

extern "C" void kernel_launch(void* const* d_in, const int* in_sizes, int n_in,
                              void* d_out, int out_size, void* d_ws, size_t ws_size,
                              hipStream_t stream) {
    const float* x   = (const float*)d_in[0];
    const float* eps = (const float*)d_in[1];
    const float* W1  = (const float*)d_in[2];
    const float* b1  = (const float*)d_in[3];
    const float* g1  = (const float*)d_in[4];
    const float* be1 = (const float*)d_in[5];
    const float* m1  = (const float*)d_in[6];
    const float* v1  = (const float*)d_in[7];
    const float* W2  = (const float*)d_in[8];
    const float* b2  = (const float*)d_in[9];
    const float* g2  = (const float*)d_in[10];
    const float* be2 = (const float*)d_in[11];
    const float* m2  = (const float*)d_in[12];
    const float* v2  = (const float*)d_in[13];
    const int*   ei  = (const int*)d_in[14];
    int nE = in_sizes[14] / 2;
    const int* src = ei;
    const int* dst = ei + nE;

    // ws layout (all rebuilt every call):
    char* ws = (char*)d_ws;
    int*          cursor  = (int*)(ws + 0);                 // NBK ints
    int*          rowptr  = (int*)(ws + 4096);              // (N+1) ints -> 404,100
    int*          csr_src = (int*)(ws + 405504);            // nE ints -> 6,805,504
    unsigned int* pairs   = (unsigned int*)(ws + 6806528);  // 9.63MB -> 16,440,320
    _Float16*     x16     = (_Float16*)(ws + 16441344);     // 25.6MB -> 42,041,344
    _Float16*     h16     = (_Float16*)(ws + 42041344);     // 25.6MB -> 67,641,344

    // 1) cursor=0; fused binscatter + cvt; bucket_fill (bscan folded)
    hipMemsetAsync(cursor, 0, NBK * sizeof(int), stream);
    bin_cvt_kernel<<<BIN_BLOCKS + CVT_BLOCKS, 256, 0, stream>>>(src, dst, cursor, pairs, nE,
                                                                x, x16);
    bucket_fill_kernel<<<NBK, 512, 0, stream>>>(pairs, cursor, rowptr, csr_src);

    // 2) gather-sum -> h16 (ws)
    gather_kernel<<<N_NODES / 16, 256, 0, stream>>>(x, x16, eps, rowptr, csr_src, h16);

    // 3) fused MLP -> out (fp32)
    mlp_fused_kernel<<<GEMM_GRID, 512, 0, stream>>>(h16, W1, b1, g1, be1, m1, v1,
                                                    W2, b2, g2, be2, m2, v2, (float*)d_out);
}